// Round 2
// baseline (1008.556 us; speedup 1.0000x reference)
//
#include <hip/hip_runtime.h>
#include <hip/hip_bf16.h>
#include <stdint.h>

// Problem constants: B=4, S=1024, D=1024, H=16, HD=64, L=6, OUT=512
#define BATCH 4
#define SEQ   1024
#define DIM   1024
#define NH    16
#define HDIM  64
#define NLAYER 6
#define NOUT  512
#define NTOK  (BATCH*SEQ)          // 4096 rows
#define LOG2E 1.44269504088896f
#define NEG_BIG (-1e30f)
#define VTS   72                   // padded LDS row stride (elements) for V^T / P

using bf16 = __hip_bfloat16;
typedef __attribute__((ext_vector_type(4))) float f32x4;
typedef __attribute__((ext_vector_type(8))) short bf16x8;

typedef __attribute__((address_space(1))) void as1_void;
typedef __attribute__((address_space(3))) void as3_void;

__device__ __forceinline__ float bf2f(short u) {
  union { unsigned int i; float f; } c;
  c.i = ((unsigned int)(unsigned short)u) << 16;
  return c.f;
}

__device__ __forceinline__ short f2bs(float f) {
  bf16 h = __float2bfloat16(f);
  return *(short*)&h;
}

// inf-free exp: clamp exponent so exp2f never sees huge/inf args (fast-math safe)
__device__ __forceinline__ float exp_clamped(float x) {
  return exp2f(fmaxf(x, -100.f) * LOG2E);
}

// flag-dependent scalar load: fp32 buffer or bf16 buffer
__device__ __forceinline__ float loadf(const void* p, size_t i, bool f32) {
  return f32 ? ((const float*)p)[i] : __bfloat162float(((const bf16*)p)[i]);
}

// async global->LDS, 16B per lane; LDS dest is wave-uniform base + lane*16
__device__ __forceinline__ void g2l16(const void* g, void* l) {
  __builtin_amdgcn_global_load_lds((const as1_void*)g, (as3_void*)l, 16, 0, 0);
}

// ---------------------------------------------------------------------------
// dtype sniffer: flag = 1 -> inputs are fp32 ; flag = 0 -> inputs are bf16
// ---------------------------------------------------------------------------
__global__ void sniff(const unsigned int* __restrict__ w, int* __restrict__ flag) {
  const int lane = threadIdx.x;            // 64 threads
  const unsigned int word = w[lane];
  const int e2 = (word >> 7) & 0xFF;
  const bool bf16ish = (e2 >= 0x60) && (e2 <= 0x8F);
  const unsigned long long m = __ballot(bf16ish);
  if (lane == 0) *flag = (__popcll(m) >= 48) ? 0 : 1;
}

// ---------------------------------------------------------------------------
// convert ALL weight tensors to bf16 workspace in ONE dispatch (graph-node
// reduction): 5 tensors of 6M elements (3072 blocks each) + wout (256 blocks).
// ---------------------------------------------------------------------------
__global__ __launch_bounds__(256) void convert_all(
    const void* __restrict__ s0, const void* __restrict__ s1,
    const void* __restrict__ s2, const void* __restrict__ s3,
    const void* __restrict__ s4, const void* __restrict__ s5,
    bf16* __restrict__ d0, bf16* __restrict__ d1, bf16* __restrict__ d2,
    bf16* __restrict__ d3, bf16* __restrict__ d4, bf16* __restrict__ d5,
    const int* __restrict__ flag) {
  int b = blockIdx.x;
  const void* src; bf16* dst;
  if      (b <  3072) { src = s0; dst = d0; }
  else if (b <  6144) { src = s1; dst = d1; b -= 3072; }
  else if (b <  9216) { src = s2; dst = d2; b -= 6144; }
  else if (b < 12288) { src = s3; dst = d3; b -= 9216; }
  else if (b < 15360) { src = s4; dst = d4; b -= 12288; }
  else                { src = s5; dst = d5; b -= 15360; }
  const size_t i = ((size_t)b * 256 + threadIdx.x) * 8;
  if (*flag) {
    const float* s = (const float*)src + i;
#pragma unroll
    for (int e = 0; e < 8; ++e) dst[i + e] = __float2bfloat16(s[e]);
  } else {
    *(bf16x8*)(dst + i) = *(const bf16x8*)((const bf16*)src + i);
  }
}

// ---------------------------------------------------------------------------
// GEMM 128x128 tile (m97 structure): C = A[M,K] * W[N,K]^T
// EPI 2: flag ? fp32 store : bf16 store.  (used by gemm_out only)
// ---------------------------------------------------------------------------
template<int EPI>
__device__ __forceinline__ void gemm_body(const bf16* __restrict__ A,
                                          const bf16* __restrict__ W,
                                          void* __restrict__ C,
                                          const int* __restrict__ flag,
                                          int N, int m0, int n0) {
  __shared__ __align__(16) bf16 lA[128 * 32];
  __shared__ __align__(16) bf16 lB[128 * 32];
  const int tid  = threadIdx.x;
  const int wave = tid >> 6;
  const int lane = tid & 63;
  const int quad = lane >> 4;
  const int l16  = lane & 15;
  const int wm = (wave >> 1) * 64;
  const int wn = (wave & 1) * 64;
  const int K = DIM;

  const int r0 = tid >> 2;
  const int c0 = (tid & 3) * 8;
  const int r1 = (tid + 256) >> 2;

  bool f32out = false;
  if (EPI == 2) f32out = (*flag != 0);

  f32x4 acc[4][4];
#pragma unroll
  for (int i = 0; i < 4; ++i)
#pragma unroll
    for (int j = 0; j < 4; ++j) acc[i][j] = (f32x4){0.f, 0.f, 0.f, 0.f};

  for (int k0 = 0; k0 < K; k0 += 32) {
    __syncthreads();
    g2l16(A + (size_t)(m0 + r0) * K + k0 + c0, lA + 512 * wave);
    g2l16(A + (size_t)(m0 + r1) * K + k0 + c0, lA + 2048 + 512 * wave);
    g2l16(W + (size_t)(n0 + r0) * K + k0 + c0, lB + 512 * wave);
    g2l16(W + (size_t)(n0 + r1) * K + k0 + c0, lB + 2048 + 512 * wave);
    __builtin_amdgcn_s_waitcnt(0);
    __syncthreads();

    bf16x8 af[4], bfr[4];
#pragma unroll
    for (int i = 0; i < 4; ++i) {
      af[i]  = *(const bf16x8*)(lA + (wm + i * 16 + l16) * 32 + quad * 8);
      bfr[i] = *(const bf16x8*)(lB + (wn + i * 16 + l16) * 32 + quad * 8);
    }
#pragma unroll
    for (int i = 0; i < 4; ++i)
#pragma unroll
      for (int j = 0; j < 4; ++j)
        acc[i][j] = __builtin_amdgcn_mfma_f32_16x16x32_bf16(af[i], bfr[j], acc[i][j], 0, 0, 0);
  }

  // C/D layout: col = lane&15, row = quad*4 + reg
#pragma unroll
  for (int i = 0; i < 4; ++i) {
    const int rowb = m0 + wm + i * 16 + quad * 4;
#pragma unroll
    for (int j = 0; j < 4; ++j) {
      const int col = n0 + wn + j * 16 + l16;
#pragma unroll
      for (int r = 0; r < 4; ++r) {
        const size_t idx = (size_t)(rowb + r) * N + col;
        const float v = acc[i][j][r];
        if (EPI == 0) ((bf16*)C)[idx] = __float2bfloat16(v);
        else { if (f32out) ((float*)C)[idx] = v; else ((bf16*)C)[idx] = __float2bfloat16(v); }
      }
    }
  }
}

__global__ __launch_bounds__(256) void gemm_out(const bf16* __restrict__ A,
                                                const bf16* __restrict__ W,
                                                void* __restrict__ C,
                                                const int* __restrict__ flag) {
  gemm_body<2>(A, W, C, flag, NOUT, blockIdx.y * 128, blockIdx.x * 128);
}

// ---------------------------------------------------------------------------
// Shared fragment read for the 8-phase kernels.
// Panel LDS layout: groups (row-pairs) x 8 chunks x 16B; logical chunk
// c3 = (row&1)*4 + quad stored at c3 ^ (group&7).  Staging applies the
// inverse XOR on the per-lane GLOBAL source address (rule #21).
// ---------------------------------------------------------------------------
__device__ __forceinline__ bf16x8 rd_frag(const short* slab, int row, int quad) {
  const int g  = row >> 1;
  const int cc = (((row & 1) << 2) | quad) ^ (g & 7);
  return *(const bf16x8*)(slab + g * 64 + cc * 8);
}

// ---------------------------------------------------------------------------
// 8-phase 256x256 GEMM (T2+T3+T4+T5), C = A[M,K] * W[N,K]^T, bf16 out.
// 512 threads = 8 waves (2M x 4N).  See round-1 notes; verified correct.
// ---------------------------------------------------------------------------
__global__ __launch_bounds__(512, 2) void gemm_qkv_8p(const bf16* __restrict__ A,
                                                      const bf16* __restrict__ wq,
                                                      const bf16* __restrict__ wk,
                                                      const bf16* __restrict__ wv,
                                                      bf16* __restrict__ q,
                                                      bf16* __restrict__ k,
                                                      bf16* __restrict__ v) {
  __shared__ __align__(16) short lA[4 * 8192];   // 64 KiB
  __shared__ __align__(16) short lB[4 * 8192];   // 64 KiB

  const int bid = blockIdx.x;
  const int mt  = bid / 12;
  const int rm  = bid - mt * 12;
  const int sel = rm >> 2;
  const int n0  = (rm & 3) * 256;
  const int m0  = mt * 256;
  const bf16* W = (sel == 0) ? wq : (sel == 1 ? wk : wv);
  bf16* C       = (sel == 0) ? q  : (sel == 1 ? k  : v);

  const int tid  = threadIdx.x;
  const int wave = tid >> 6;
  const int lane = tid & 63;
  const int quad = lane >> 4;
  const int l16  = lane & 15;
  const int wr   = wave >> 2;   // M half: rows wr*128 .. +127
  const int wc   = wave & 3;    // N quarter: cols wc*64 .. +63

  const int c3   = (lane & 7) ^ (lane >> 3);
  const int sq   = c3 & 3;                       // k-chunk within panel
  const int rsub = ((lane >> 3) << 1) | (c3 >> 2);
  const size_t aOff0 = (size_t)(m0 + wave * 32 + rsub) * DIM + sq * 8;
  const size_t aOff1 = aOff0 + (size_t)16 * DIM;
  const size_t bOff0 = (size_t)(n0 + wave * 32 + rsub) * DIM + sq * 8;
  const size_t bOff1 = bOff0 + (size_t)16 * DIM;
  const int ldsW = wave * 1024;                  // shorts: wave*16 groups * 64

#define STAGE_A8(J) { short* s_ = lA + ((J) & 3) * 8192 + ldsW;                 \
    g2l16(A + aOff0 + (J) * 32, s_); g2l16(A + aOff1 + (J) * 32, s_ + 512); }
#define STAGE_B8(J) { short* s_ = lB + ((J) & 3) * 8192 + ldsW;                 \
    g2l16(W + bOff0 + (J) * 32, s_); g2l16(W + bOff1 + (J) * 32, s_ + 512); }

  f32x4 acc[8][4];
#pragma unroll
  for (int i = 0; i < 8; ++i)
#pragma unroll
    for (int jn = 0; jn < 4; ++jn) acc[i][jn] = (f32x4){0.f, 0.f, 0.f, 0.f};

  // prologue: A0 B0 A1 B1 A2 B2 B3 (7 panels); keep 3 in flight
  STAGE_A8(0); STAGE_B8(0);
  STAGE_A8(1); STAGE_B8(1);
  STAGE_A8(2); STAGE_B8(2);
  STAGE_B8(3);
  asm volatile("s_waitcnt vmcnt(6)" ::: "memory");
  __builtin_amdgcn_s_barrier();
  __builtin_amdgcn_sched_barrier(0);

  const int arow = wr * 128 + l16;
  const int brow = wc * 64 + l16;

  for (int jo = 0; jo < 32; jo += 4) {
#pragma unroll
    for (int ji = 0; ji < 4; ++ji) {
      const int j = jo + ji;
      const short* sA = lA + ji * 8192;          // slab = j & 3 == ji
      const short* sB = lB + ji * 8192;
      bf16x8 af[4], bfv[4];
      // ---- phase (j,0)
#pragma unroll
      for (int mi = 0; mi < 4; ++mi) af[mi]  = rd_frag(sA, arow + mi * 16, quad);
#pragma unroll
      for (int nj = 0; nj < 4; ++nj) bfv[nj] = rd_frag(sB, brow + nj * 16, quad);
      if (j < 29) STAGE_A8(j + 3);
      __builtin_amdgcn_s_barrier();
      asm volatile("s_waitcnt lgkmcnt(0)" ::: "memory");
      __builtin_amdgcn_sched_barrier(0);
      __builtin_amdgcn_s_setprio(1);
#pragma unroll
      for (int mi = 0; mi < 4; ++mi)
#pragma unroll
        for (int nj = 0; nj < 4; ++nj)
          acc[mi][nj] = __builtin_amdgcn_mfma_f32_16x16x32_bf16(af[mi], bfv[nj], acc[mi][nj], 0, 0, 0);
      __builtin_amdgcn_s_setprio(0);
      __builtin_amdgcn_s_barrier();
      __builtin_amdgcn_sched_barrier(0);
      // ---- phase (j,1)
#pragma unroll
      for (int mi = 0; mi < 4; ++mi) af[mi] = rd_frag(sA, arow + 64 + mi * 16, quad);
      if (j < 28) STAGE_B8(j + 4);
      __builtin_amdgcn_s_barrier();
      asm volatile("s_waitcnt lgkmcnt(0)" ::: "memory");
      __builtin_amdgcn_sched_barrier(0);
      __builtin_amdgcn_s_setprio(1);
#pragma unroll
      for (int mi = 0; mi < 4; ++mi)
#pragma unroll
        for (int nj = 0; nj < 4; ++nj)
          acc[4 + mi][nj] = __builtin_amdgcn_mfma_f32_16x16x32_bf16(af[mi], bfv[nj], acc[4 + mi][nj], 0, 0, 0);
      __builtin_amdgcn_s_setprio(0);
      if (ji & 1) {
        if (j < 28) { asm volatile("s_waitcnt vmcnt(6)" ::: "memory"); }
        else        { asm volatile("s_waitcnt vmcnt(0)" ::: "memory"); }
      }
      __builtin_amdgcn_s_barrier();
      __builtin_amdgcn_sched_barrier(0);
    }
  }
#undef STAGE_A8
#undef STAGE_B8

  // epilogue: bf16 store; C/D layout col = l16, row = quad*4 + rr
#pragma unroll
  for (int mi = 0; mi < 8; ++mi) {
    const int rowb = m0 + wr * 128 + mi * 16 + quad * 4;
#pragma unroll
    for (int nj = 0; nj < 4; ++nj) {
      const int col = n0 + wc * 64 + nj * 16 + l16;
#pragma unroll
      for (int rr = 0; rr < 4; ++rr)
        C[(size_t)(rowb + rr) * DIM + col] = __float2bfloat16(acc[mi][nj][rr]);
    }
  }
}

// ---------------------------------------------------------------------------
// 8-phase 256x64 GEMM with fp32 += epilogue (residual adds).
// Same template as gemm_qkv_8p; geometry: 16x16 = 256 blocks (1/CU, all CUs),
// 8 waves (4M x 2N), per-wave 64x32 out (acc[4][2]).
// B panels (64x32 = 4 KiB) staged by waves 0-3 only -> per-wave-class counted
// vmcnt: staging waves keep {B(j+3),A(j+3),B(j+4)} = 4 loads in flight,
// A-only waves keep {A(j+3)} = 2.  Ledger re-derived by hand: vmcnt at odd j
// guarantees panels j+1 and j+2 landed; ring distances (A=3, B=4) protected
// by the phase-closing barriers.  K-accumulation order identical to the old
// gemm_add -> identical numerics.
// ---------------------------------------------------------------------------
__global__ __launch_bounds__(512, 2) void gemm_add_8p(const bf16* __restrict__ A,
                                                      const bf16* __restrict__ W,
                                                      float* __restrict__ C) {
  __shared__ __align__(16) short lA[4 * 8192];   // 64 KiB: A panels 256x32
  __shared__ __align__(16) short lB[4 * 2048];   // 16 KiB: B panels 64x32

  const int bid = blockIdx.x;
  const int m0 = (bid >> 4) * 256;
  const int n0 = (bid & 15) * 64;

  const int tid  = threadIdx.x;
  const int wave = tid >> 6;
  const int lane = tid & 63;
  const int quad = lane >> 4;
  const int l16  = lane & 15;
  const int wr   = wave >> 1;    // 0..3: 64-row stripe
  const int wc   = wave & 1;     // 0..1: 32-col stripe

  const int c3   = (lane & 7) ^ (lane >> 3);
  const int sq   = c3 & 3;
  const int rsub = ((lane >> 3) << 1) | (c3 >> 2);
  const size_t aOff0 = (size_t)(m0 + wave * 32 + rsub) * DIM + sq * 8;
  const size_t aOff1 = aOff0 + (size_t)16 * DIM;
  const size_t bOff  = (size_t)(n0 + wave * 16 + rsub) * DIM + sq * 8; // waves 0-3
  const int ldsWA = wave * 1024;   // shorts
  const int ldsWB = wave * 512;    // shorts, waves 0-3

#define SA8(J) { short* s_ = lA + ((J) & 3) * 8192 + ldsWA;                     \
    g2l16(A + aOff0 + (J) * 32, s_); g2l16(A + aOff1 + (J) * 32, s_ + 512); }
#define SB8(J) if (wave < 4) { short* s_ = lB + ((J) & 3) * 2048 + ldsWB;       \
    g2l16(W + bOff + (J) * 32, s_); }

  f32x4 acc[4][2];
#pragma unroll
  for (int i = 0; i < 4; ++i)
#pragma unroll
    for (int jn = 0; jn < 2; ++jn) acc[i][jn] = (f32x4){0.f, 0.f, 0.f, 0.f};

  // prologue: A0 B0 A1 B1 A2 B2 B3; staging waves: 10 loads, need first 6 ->
  // vmcnt(4); A-only waves: 6 loads, need first 4 -> vmcnt(2).
  SA8(0); SB8(0);
  SA8(1); SB8(1);
  SA8(2); SB8(2);
  SB8(3);
  if (wave < 4) { asm volatile("s_waitcnt vmcnt(4)" ::: "memory"); }
  else          { asm volatile("s_waitcnt vmcnt(2)" ::: "memory"); }
  __builtin_amdgcn_s_barrier();
  __builtin_amdgcn_sched_barrier(0);

  const int arow = wr * 64 + l16;
  const int brow = wc * 32 + l16;

  for (int jo = 0; jo < 32; jo += 4) {
#pragma unroll
    for (int ji = 0; ji < 4; ++ji) {
      const int j = jo + ji;
      const short* sA = lA + ji * 8192;
      const short* sB = lB + ji * 2048;
      bf16x8 af[2], bfv[2];
      // ---- phase (j,0): rows arow+0,+16; both B stripes
      af[0]  = rd_frag(sA, arow,      quad);
      af[1]  = rd_frag(sA, arow + 16, quad);
      bfv[0] = rd_frag(sB, brow,      quad);
      bfv[1] = rd_frag(sB, brow + 16, quad);
      if (j < 29) SA8(j + 3);
      __builtin_amdgcn_s_barrier();
      asm volatile("s_waitcnt lgkmcnt(0)" ::: "memory");
      __builtin_amdgcn_sched_barrier(0);
      __builtin_amdgcn_s_setprio(1);
      acc[0][0] = __builtin_amdgcn_mfma_f32_16x16x32_bf16(af[0], bfv[0], acc[0][0], 0, 0, 0);
      acc[0][1] = __builtin_amdgcn_mfma_f32_16x16x32_bf16(af[0], bfv[1], acc[0][1], 0, 0, 0);
      acc[1][0] = __builtin_amdgcn_mfma_f32_16x16x32_bf16(af[1], bfv[0], acc[1][0], 0, 0, 0);
      acc[1][1] = __builtin_amdgcn_mfma_f32_16x16x32_bf16(af[1], bfv[1], acc[1][1], 0, 0, 0);
      __builtin_amdgcn_s_setprio(0);
      __builtin_amdgcn_s_barrier();
      __builtin_amdgcn_sched_barrier(0);
      // ---- phase (j,1): rows arow+32,+48; reuse bfv
      af[0] = rd_frag(sA, arow + 32, quad);
      af[1] = rd_frag(sA, arow + 48, quad);
      if (j < 28) SB8(j + 4);
      __builtin_amdgcn_s_barrier();
      asm volatile("s_waitcnt lgkmcnt(0)" ::: "memory");
      __builtin_amdgcn_sched_barrier(0);
      __builtin_amdgcn_s_setprio(1);
      acc[2][0] = __builtin_amdgcn_mfma_f32_16x16x32_bf16(af[0], bfv[0], acc[2][0], 0, 0, 0);
      acc[2][1] = __builtin_amdgcn_mfma_f32_16x16x32_bf16(af[0], bfv[1], acc[2][1], 0, 0, 0);
      acc[3][0] = __builtin_amdgcn_mfma_f32_16x16x32_bf16(af[1], bfv[0], acc[3][0], 0, 0, 0);
      acc[3][1] = __builtin_amdgcn_mfma_f32_16x16x32_bf16(af[1], bfv[1], acc[3][1], 0, 0, 0);
      __builtin_amdgcn_s_setprio(0);
      if (ji & 1) {
        if (j < 28) {
          if (wave < 4) { asm volatile("s_waitcnt vmcnt(4)" ::: "memory"); }
          else          { asm volatile("s_waitcnt vmcnt(2)" ::: "memory"); }
        } else {
          asm volatile("s_waitcnt vmcnt(0)" ::: "memory");
        }
      }
      __builtin_amdgcn_s_barrier();
      __builtin_amdgcn_sched_barrier(0);
    }
  }
#undef SA8
#undef SB8

  // epilogue: fp32 +=; C/D layout col = l16, row = quad*4 + rr
#pragma unroll
  for (int mi = 0; mi < 4; ++mi) {
    const int rowb = m0 + wr * 64 + mi * 16 + quad * 4;
#pragma unroll
    for (int nj = 0; nj < 2; ++nj) {
      const int col = n0 + wc * 32 + nj * 16 + l16;
#pragma unroll
      for (int rr = 0; rr < 4; ++rr)
        C[(size_t)(rowb + rr) * DIM + col] += acc[mi][nj][rr];
    }
  }
}

// ---------------------------------------------------------------------------
// h = x + pe  (flag-dependent input dtype), fp32 residual stream
// ---------------------------------------------------------------------------
__global__ __launch_bounds__(256) void add_pe(const void* __restrict__ x,
                                              const void* __restrict__ pe,
                                              float* __restrict__ h,
                                              const int* __restrict__ flag) {
  const bool f32 = (*flag != 0);
  const size_t i = (size_t)blockIdx.x * 256 + threadIdx.x;
  h[i] = loadf(x, i, f32) + loadf(pe, i & (SEQ * DIM - 1), f32);
}

// ---------------------------------------------------------------------------
// LayerNorm over D=1024: one 256-thread block per row, fp32 in, bf16 out.
// ---------------------------------------------------------------------------
__global__ __launch_bounds__(256) void layernorm(const float* __restrict__ x,
                                                 const void* __restrict__ g,
                                                 const void* __restrict__ b,
                                                 int loff,
                                                 bf16* __restrict__ y,
                                                 const int* __restrict__ flag) {
  const bool f32 = (*flag != 0);
  const int row = blockIdx.x;
  const int tid = threadIdx.x;
  const int wave = tid >> 6;
  const float* xr = x + (size_t)row * DIM;
  __shared__ float red[8];

  float v[4];
  float s = 0.f;
#pragma unroll
  for (int i = 0; i < 4; ++i) { v[i] = xr[tid + 256 * i]; s += v[i]; }
#pragma unroll
  for (int off = 32; off >= 1; off >>= 1) s += __shfl_xor(s, off);
  if ((tid & 63) == 0) red[wave] = s;
  __syncthreads();
  const float mu = (red[0] + red[1] + red[2] + red[3]) * (1.f / DIM);

  float vs = 0.f;
#pragma unroll
  for (int i = 0; i < 4; ++i) { const float d = v[i] - mu; vs += d * d; }
#pragma unroll
  for (int off = 32; off >= 1; off >>= 1) vs += __shfl_xor(vs, off);
  if ((tid & 63) == 0) red[4 + wave] = vs;
  __syncthreads();
  const float var = (red[4] + red[5] + red[6] + red[7]) * (1.f / DIM);
  const float rs = rsqrtf(var + 1e-5f);

#pragma unroll
  for (int i = 0; i < 4; ++i) {
    const int d = tid + 256 * i;
    const float gv = loadf(g, (size_t)loff + d, f32);
    const float bv = loadf(b, (size_t)loff + d, f32);
    y[(size_t)row * DIM + d] = __float2bfloat16((v[i] - mu) * rs * gv + bv);
  }
}

// ---------------------------------------------------------------------------
// MFMA flash attention, FIXED-MAX softmax (m=0): scores bounded (|s|<=26),
// so no max reduction, no alpha rescale; l reduced once at the end.
// Block = (b, h, 64 q-rows); 4 waves, 16 q-rows/wave.
// ---------------------------------------------------------------------------
__global__ __launch_bounds__(256, 2) void attn_flash(const bf16* __restrict__ q,
                                                     const bf16* __restrict__ k,
                                                     const bf16* __restrict__ v,
                                                     bf16* __restrict__ o) {
  __shared__ __align__(16) short lK[64 * 64];        // [key][dim], chunk-swizzled
  __shared__ __align__(16) short lVT[64 * VTS];      // [dim][key], kk-swizzled
  __shared__ __align__(16) short lP[4 * 16 * VTS];   // per-wave P, padded

  const int idx = blockIdx.x;
  const int qt = (SEQ / 64 - 1) - (idx >> 6);        // heavy blocks first
  const int bh = idx & 63;
  const int hh = bh & (NH - 1);
  const int bb = bh >> 4;
  const int q0 = qt * 64;

  const int tid = threadIdx.x;
  const int wave = tid >> 6;
  const int lane = tid & 63;
  const int quad = lane >> 4;
  const int l16 = lane & 15;

  const size_t base = (size_t)bb * SEQ * DIM + hh * HDIM;
  const int qlo = q0 + wave * 16;                    // this wave's first q row

  // Q fragments (A-layout: m=l16, k=quad*8+j), pre-scaled by 1/sqrt(HD)
  bf16x8 qf[2];
  {
    const bf16* qr = q + base + (size_t)(qlo + l16) * DIM;
#pragma unroll
    for (int kc = 0; kc < 2; ++kc) {
      bf16x8 t = *(const bf16x8*)(qr + kc * 32 + quad * 8);
      bf16x8 sq;
#pragma unroll
      for (int e = 0; e < 8; ++e) sq[e] = f2bs(bf2f(t[e]) * 0.125f);
      qf[kc] = sq;
    }
  }

  float l_acc[4] = {0.f, 0.f, 0.f, 0.f};   // per-lane partial sums (rows)
  f32x4 oacc[4];
#pragma unroll
  for (int nb = 0; nb < 4; ++nb) oacc[nb] = (f32x4){0.f, 0.f, 0.f, 0.f};

  short* lPw = lP + wave * 16 * VTS;
  const int nt = qt + 1;

  for (int t = 0; t < nt; ++t) {
    const int kbase = t * 64;
    __syncthreads();   // previous tile's LDS reads complete

    // --- stage K tile [64 keys][64 dims] via g2l16, chunk-swizzled
    {
      const int r8 = lane >> 3;                 // row within 8-row group
      const int cc = (lane & 7) ^ r8;           // swizzled 16B chunk
#pragma unroll
      for (int c = 0; c < 2; ++c) {
        const int row = wave * 16 + c * 8 + r8; // key within tile
        g2l16(k + base + (size_t)(kbase + row) * DIM + cc * 8,
              lK + (wave * 16 + c * 8) * 64);
      }
    }

    // --- stage V^T [dim][key] via regs, kk XOR-swizzled by (dim>>3)&7
    bf16x8 vch[2];
#pragma unroll
    for (int c2 = 0; c2 < 2; ++c2) {
      const int cid = tid + c2 * 256;
      const int kk = cid >> 3;
      const int d0 = (cid & 7) * 8;
      vch[c2] = *(const bf16x8*)(v + base + (size_t)(kbase + kk) * DIM + d0);
    }
#pragma unroll
    for (int c2 = 0; c2 < 2; ++c2) {
      const int cid = tid + c2 * 256;
      const int kk = cid >> 3;
      const int d0 = (cid & 7) * 8;
#pragma unroll
      for (int e = 0; e < 8; ++e) {
        const int d = d0 + e;
        const int kks = kk ^ (((d >> 3) & 7) << 3);
        lVT[d * VTS + kks] = vch[c2][e];
      }
    }
    __builtin_amdgcn_s_waitcnt(0);   // drain g2l16 before barrier
    __syncthreads();

    // --- S = Q K^T : 16 q-rows x 64 keys per wave
    f32x4 s[4];
#pragma unroll
    for (int nb = 0; nb < 4; ++nb) {
      f32x4 acc = (f32x4){0.f, 0.f, 0.f, 0.f};
      const int n = nb * 16 + l16;              // key within tile
#pragma unroll
      for (int kc = 0; kc < 2; ++kc) {
        const int cidx = (kc * 4 + quad) ^ (n & 7);
        bf16x8 kf = *(const bf16x8*)(lK + n * 64 + cidx * 8);
        acc = __builtin_amdgcn_mfma_f32_16x16x32_bf16(qf[kc], kf, acc, 0, 0, 0);
      }
      s[nb] = acc;
    }

    // --- causal mask (only the diagonal tile needs it)
    if (kbase + 63 > qlo) {
#pragma unroll
      for (int nb = 0; nb < 4; ++nb) {
        const int j = kbase + nb * 16 + l16;
#pragma unroll
        for (int r = 0; r < 4; ++r)
          if (j > qlo + quad * 4 + r) s[nb][r] = NEG_BIG;
      }
    }

    // --- fixed-max softmax: p = exp(s); accumulate l per-lane; P -> LDS
#pragma unroll
    for (int nb = 0; nb < 4; ++nb) {
#pragma unroll
      for (int r = 0; r < 4; ++r) {
        const float p = exp_clamped(s[nb][r]);
        l_acc[r] += p;
        lPw[(quad * 4 + r) * VTS + nb * 16 + l16] = f2bs(p);
      }
    }

    // --- P back from LDS in A-layout (same wave; lgkm drain)
    __builtin_amdgcn_s_waitcnt(0);
    bf16x8 pf[2];
#pragma unroll
    for (int kc = 0; kc < 2; ++kc)
      pf[kc] = *(const bf16x8*)(lPw + l16 * VTS + kc * 32 + quad * 8);

    // --- O += P V  (b-frag from V^T rows, undo kk swizzle)
#pragma unroll
    for (int nb = 0; nb < 4; ++nb) {
      const int n = nb * 16 + l16;              // output dim
      const int swz = ((n >> 3) & 7) << 3;
#pragma unroll
      for (int kc = 0; kc < 2; ++kc) {
        const int kchunk = (kc * 32 + quad * 8) ^ swz;
        bf16x8 vf = *(const bf16x8*)(lVT + n * VTS + kchunk);
        oacc[nb] = __builtin_amdgcn_mfma_f32_16x16x32_bf16(pf[kc], vf, oacc[nb], 0, 0, 0);
      }
    }
  }

  // --- reduce l across the 16-lane key groups (once), normalize, store
  float linv[4];
#pragma unroll
  for (int r = 0; r < 4; ++r) {
    float ts = l_acc[r];
#pragma unroll
    for (int off = 8; off >= 1; off >>= 1) ts += __shfl_xor(ts, off);
    linv[r] = 1.f / ts;
  }
#pragma unroll
  for (int nb = 0; nb < 4; ++nb)
#pragma unroll
    for (int r = 0; r < 4; ++r) {
      const int qrow = q0 + wave * 16 + quad * 4 + r;
      o[base + (size_t)qrow * DIM + nb * 16 + l16] =
          __float2bfloat16(oacc[nb][r] * linv[r]);
    }
}

// ---------------------------------------------------------------------------
extern "C" void kernel_launch(void* const* d_in, const int* in_sizes, int n_in,
                              void* d_out, int out_size, void* d_ws, size_t ws_size,
                              hipStream_t stream) {
  const void* x    = d_in[0];
  const void* pe   = d_in[1];
  // d_in[2] = mask (causal; handled analytically; never read)
  const void* ln1g = d_in[3];
  const void* ln1b = d_in[4];
  const void* wq   = d_in[5];
  const void* wk   = d_in[6];
  const void* wv   = d_in[7];
  const void* wo   = d_in[8];
  const void* ln2g = d_in[9];
  const void* ln2b = d_in[10];
  const void* wf   = d_in[11];
  const void* lnfg = d_in[12];
  const void* lnfb = d_in[13];
  const void* wout = d_in[14];

  const size_t MB = 1u << 20;
  char* ws = (char*)d_ws;
  int*  flag = (int*)ws;                          // 4 B (1 MB reserved)
  bf16* wqc  = (bf16*)(ws + 1 * MB);              // 12 MB (6 layers)
  bf16* wkc  = (bf16*)(ws + 13 * MB);
  bf16* wvc  = (bf16*)(ws + 25 * MB);
  bf16* woc  = (bf16*)(ws + 37 * MB);
  bf16* wfc  = (bf16*)(ws + 49 * MB);
  bf16* woutc= (bf16*)(ws + 61 * MB);             // 1 MB
  float* h   = (float*)(ws + 62 * MB);            // 16 MB fp32 residual
  bf16* hn   = (bf16*)(ws + 78 * MB);             // 8 MB
  bf16* qb   = (bf16*)(ws + 86 * MB);
  bf16* kb   = (bf16*)(ws + 94 * MB);
  bf16* vb   = (bf16*)(ws + 102 * MB);            // end: 110 MB
  bf16* ab   = hn;   // attn out aliases hn (ln1 output dead after QKV gemm)

  sniff<<<1, 64, 0, stream>>>((const unsigned int*)wq, flag);

  // single fused weight-convert dispatch: 5x3072 blocks + 256 blocks
  convert_all<<<15616, 256, 0, stream>>>(wq, wk, wv, wo, wf, wout,
                                         wqc, wkc, wvc, woc, wfc, woutc, flag);

  add_pe<<<NTOK * DIM / 256, 256, 0, stream>>>(x, pe, h, flag);

  for (int l = 0; l < NLAYER; ++l) {
    const size_t woff = (size_t)l << 20;          // l * 1024*1024 elements
    const int poff = l * DIM;                     // element offset for gamma/beta
    layernorm<<<NTOK, 256, 0, stream>>>(h, ln1g, ln1b, poff, hn, flag);
    gemm_qkv_8p<<<dim3(192), 512, 0, stream>>>(hn, wqc + woff, wkc + woff, wvc + woff,
                                               qb, kb, vb);
    attn_flash<<<dim3(BATCH * NH * (SEQ / 64)), 256, 0, stream>>>(qb, kb, vb, ab);
    gemm_add_8p<<<dim3(256), 512, 0, stream>>>(ab, woc + woff, h);
    layernorm<<<NTOK, 256, 0, stream>>>(h, ln2g, ln2b, poff, hn, flag);
    gemm_add_8p<<<dim3(256), 512, 0, stream>>>(hn, wfc + woff, h);
  }

  layernorm<<<NTOK, 256, 0, stream>>>(h, lnfg, lnfb, 0, hn, flag);
  gemm_out<<<dim3(4, 32), 256, 0, stream>>>(hn, woutc, d_out, flag);
}

// Round 5
// 966.445 us; speedup vs baseline: 1.0436x; 1.0436x over previous
//
#include <hip/hip_runtime.h>
#include <hip/hip_bf16.h>
#include <stdint.h>

// Problem constants: B=4, S=1024, D=1024, H=16, HD=64, L=6, OUT=512
#define BATCH 4
#define SEQ   1024
#define DIM   1024
#define NH    16
#define HDIM  64
#define NLAYER 6
#define NOUT  512
#define NTOK  (BATCH*SEQ)          // 4096 rows
#define LOG2E 1.44269504088896f
#define NEG_BIG (-1e30f)
#define VTS   72                   // padded LDS row stride (elements) for V^T / P

using bf16 = __hip_bfloat16;
typedef __attribute__((ext_vector_type(4))) float f32x4;
typedef __attribute__((ext_vector_type(8))) short bf16x8;

typedef __attribute__((address_space(1))) void as1_void;
typedef __attribute__((address_space(3))) void as3_void;

__device__ __forceinline__ float bf2f(short u) {
  union { unsigned int i; float f; } c;
  c.i = ((unsigned int)(unsigned short)u) << 16;
  return c.f;
}

__device__ __forceinline__ short f2bs(float f) {
  bf16 h = __float2bfloat16(f);
  return *(short*)&h;
}

// inf-free exp: clamp exponent so exp2f never sees huge/inf args (fast-math safe)
__device__ __forceinline__ float exp_clamped(float x) {
  return exp2f(fmaxf(x, -100.f) * LOG2E);
}

// flag-dependent scalar load: fp32 buffer or bf16 buffer
__device__ __forceinline__ float loadf(const void* p, size_t i, bool f32) {
  return f32 ? ((const float*)p)[i] : __bfloat162float(((const bf16*)p)[i]);
}

// async global->LDS, 16B per lane; LDS dest is wave-uniform base + lane*16
__device__ __forceinline__ void g2l16(const void* g, void* l) {
  __builtin_amdgcn_global_load_lds((const as1_void*)g, (as3_void*)l, 16, 0, 0);
}

// ---------------------------------------------------------------------------
// dtype sniffer: flag = 1 -> inputs are fp32 ; flag = 0 -> inputs are bf16
// ---------------------------------------------------------------------------
__global__ void sniff(const unsigned int* __restrict__ w, int* __restrict__ flag) {
  const int lane = threadIdx.x;            // 64 threads
  const unsigned int word = w[lane];
  const int e2 = (word >> 7) & 0xFF;
  const bool bf16ish = (e2 >= 0x60) && (e2 <= 0x8F);
  const unsigned long long m = __ballot(bf16ish);
  if (lane == 0) *flag = (__popcll(m) >= 48) ? 0 : 1;
}

// ---------------------------------------------------------------------------
// Weight convert.  flag==0 (bf16 inputs): early-exit -- GEMMs read the
// ORIGINAL weight buffers directly (device-side pointer select).
// flag==1 (fp32): vectorized convert, grid-stride (2048 blocks):
// 2x f32x4 loads -> one 16B bf16x8 store per vec8.
// ---------------------------------------------------------------------------
#define CV_BIG 786432   /* vec8 count per [L,D,D] tensor = 6*1024*1024/8 */
#define CV_TOT (5 * CV_BIG + 65536)   /* + wout 512*1024/8 */

__global__ __launch_bounds__(256) void convert_all(
    const float* __restrict__ s0, const float* __restrict__ s1,
    const float* __restrict__ s2, const float* __restrict__ s3,
    const float* __restrict__ s4, const float* __restrict__ s5,
    bf16* __restrict__ d0, bf16* __restrict__ d1, bf16* __restrict__ d2,
    bf16* __restrict__ d3, bf16* __restrict__ d4, bf16* __restrict__ d5,
    const int* __restrict__ flag) {
  if (*flag == 0) return;
  for (size_t vi = (size_t)blockIdx.x * 256 + threadIdx.x; vi < CV_TOT;
       vi += (size_t)gridDim.x * 256) {
    const int t = (int)(vi / CV_BIG);            // 0..4 big, 5 = wout
    const float* s; bf16* d;
    switch (t) {
      case 0: s = s0; d = d0; break;
      case 1: s = s1; d = d1; break;
      case 2: s = s2; d = d2; break;
      case 3: s = s3; d = d3; break;
      case 4: s = s4; d = d4; break;
      default: s = s5; d = d5; break;
    }
    const size_t off = (vi - (size_t)t * CV_BIG) * 8;
    const f32x4 a = *(const f32x4*)(s + off);
    const f32x4 b = *(const f32x4*)(s + off + 4);
    bf16x8 o;
    o[0] = f2bs(a[0]); o[1] = f2bs(a[1]); o[2] = f2bs(a[2]); o[3] = f2bs(a[3]);
    o[4] = f2bs(b[0]); o[5] = f2bs(b[1]); o[6] = f2bs(b[2]); o[7] = f2bs(b[3]);
    *(bf16x8*)(d + off) = o;
  }
}

// ---------------------------------------------------------------------------
// GEMM 128x128 tile (m97 structure, prior-session-validated):
// C = A[M,K] * W[N,K]^T.
// EPI 0: bf16 store.  EPI 2: flag ? fp32 store : bf16 store.
// ---------------------------------------------------------------------------
template<int EPI>
__device__ __forceinline__ void gemm_body(const bf16* __restrict__ A,
                                          const bf16* __restrict__ W,
                                          void* __restrict__ C,
                                          const int* __restrict__ flag,
                                          int N, int m0, int n0) {
  __shared__ __align__(16) bf16 lA[128 * 32];
  __shared__ __align__(16) bf16 lB[128 * 32];
  const int tid  = threadIdx.x;
  const int wave = tid >> 6;
  const int lane = tid & 63;
  const int quad = lane >> 4;
  const int l16  = lane & 15;
  const int wm = (wave >> 1) * 64;
  const int wn = (wave & 1) * 64;
  const int K = DIM;

  const int r0 = tid >> 2;
  const int c0 = (tid & 3) * 8;
  const int r1 = (tid + 256) >> 2;

  bool f32out = false;
  if (EPI == 2) f32out = (*flag != 0);

  f32x4 acc[4][4];
#pragma unroll
  for (int i = 0; i < 4; ++i)
#pragma unroll
    for (int j = 0; j < 4; ++j) acc[i][j] = (f32x4){0.f, 0.f, 0.f, 0.f};

  for (int k0 = 0; k0 < K; k0 += 32) {
    __syncthreads();
    g2l16(A + (size_t)(m0 + r0) * K + k0 + c0, lA + 512 * wave);
    g2l16(A + (size_t)(m0 + r1) * K + k0 + c0, lA + 2048 + 512 * wave);
    g2l16(W + (size_t)(n0 + r0) * K + k0 + c0, lB + 512 * wave);
    g2l16(W + (size_t)(n0 + r1) * K + k0 + c0, lB + 2048 + 512 * wave);
    __builtin_amdgcn_s_waitcnt(0);
    __syncthreads();

    bf16x8 af[4], bfr[4];
#pragma unroll
    for (int i = 0; i < 4; ++i) {
      af[i]  = *(const bf16x8*)(lA + (wm + i * 16 + l16) * 32 + quad * 8);
      bfr[i] = *(const bf16x8*)(lB + (wn + i * 16 + l16) * 32 + quad * 8);
    }
#pragma unroll
    for (int i = 0; i < 4; ++i)
#pragma unroll
      for (int j = 0; j < 4; ++j)
        acc[i][j] = __builtin_amdgcn_mfma_f32_16x16x32_bf16(af[i], bfr[j], acc[i][j], 0, 0, 0);
  }

  // C/D layout: col = lane&15, row = quad*4 + reg
#pragma unroll
  for (int i = 0; i < 4; ++i) {
    const int rowb = m0 + wm + i * 16 + quad * 4;
#pragma unroll
    for (int j = 0; j < 4; ++j) {
      const int col = n0 + wn + j * 16 + l16;
#pragma unroll
      for (int r = 0; r < 4; ++r) {
        const size_t idx = (size_t)(rowb + r) * N + col;
        const float v = acc[i][j][r];
        if (EPI == 0) ((bf16*)C)[idx] = __float2bfloat16(v);
        else { if (f32out) ((float*)C)[idx] = v; else ((bf16*)C)[idx] = __float2bfloat16(v); }
      }
    }
  }
}

__global__ __launch_bounds__(256) void gemm_out(const bf16* __restrict__ A,
                                                const bf16* __restrict__ Wc,
                                                const bf16* __restrict__ Wo,
                                                void* __restrict__ C,
                                                const int* __restrict__ flag) {
  const bf16* W = (*flag != 0) ? Wc : Wo;
  gemm_body<2>(A, W, C, flag, NOUT, blockIdx.y * 128, blockIdx.x * 128);
}

// qkv: grid (24, 32) -- gx = sel*8 + n-tile; 768 blocks total (round-0
// validated structure; 8-phase variant reverted after intermittent
// post-timing divergence in round 3).
__global__ __launch_bounds__(256) void gemm_qkv(const bf16* __restrict__ A,
                                                const bf16* __restrict__ cq,
                                                const bf16* __restrict__ ck,
                                                const bf16* __restrict__ cvv,
                                                const bf16* __restrict__ oq,
                                                const bf16* __restrict__ ok,
                                                const bf16* __restrict__ ov,
                                                bf16* __restrict__ q,
                                                bf16* __restrict__ k,
                                                bf16* __restrict__ v,
                                                const int* __restrict__ flag) {
  const int gx = blockIdx.x;
  const int sel = gx >> 3;
  const int n0 = (gx & 7) * 128;
  const bool f32 = (*flag != 0);
  const bf16* W = (sel == 0) ? (f32 ? cq : oq)
                 : (sel == 1) ? (f32 ? ck : ok)
                              : (f32 ? cvv : ov);
  bf16* C = (sel == 0) ? q : (sel == 1 ? k : v);
  gemm_body<0>(A, W, C, nullptr, DIM, blockIdx.y * 128, n0);
}

// ---------------------------------------------------------------------------
// GEMM 64x128 tile, full-K, fp32 += epilogue (residual adds).  Round-0
// version (512 blocks -> 2 blocks/CU; cross-block overlap hides barriers).
// ---------------------------------------------------------------------------
__device__ __forceinline__ void gemm64_body(const bf16* __restrict__ A,
                                            const bf16* __restrict__ W,
                                            float* __restrict__ C,
                                            int N, int m0, int n0) {
  __shared__ __align__(16) bf16 lA[64 * 32];
  __shared__ __align__(16) bf16 lB[128 * 32];
  const int tid  = threadIdx.x;
  const int wave = tid >> 6;
  const int lane = tid & 63;
  const int quad = lane >> 4;
  const int l16  = lane & 15;
  const int wm = (wave >> 1) * 32;
  const int wn = (wave & 1) * 64;
  const int K = DIM;

  const int r0 = tid >> 2;             // 0..63
  const int c0 = (tid & 3) * 8;
  const int r1 = (tid + 256) >> 2;     // 64..127 (B second half)

  f32x4 acc[2][4];
#pragma unroll
  for (int i = 0; i < 2; ++i)
#pragma unroll
    for (int j = 0; j < 4; ++j) acc[i][j] = (f32x4){0.f, 0.f, 0.f, 0.f};

  for (int k0 = 0; k0 < K; k0 += 32) {
    __syncthreads();
    g2l16(A + (size_t)(m0 + r0) * K + k0 + c0, lA + 512 * wave);
    g2l16(W + (size_t)(n0 + r0) * K + k0 + c0, lB + 512 * wave);
    g2l16(W + (size_t)(n0 + r1) * K + k0 + c0, lB + 2048 + 512 * wave);
    __builtin_amdgcn_s_waitcnt(0);
    __syncthreads();

    bf16x8 af[2], bfr[4];
#pragma unroll
    for (int i = 0; i < 2; ++i)
      af[i]  = *(const bf16x8*)(lA + (wm + i * 16 + l16) * 32 + quad * 8);
#pragma unroll
    for (int j = 0; j < 4; ++j)
      bfr[j] = *(const bf16x8*)(lB + (wn + j * 16 + l16) * 32 + quad * 8);
#pragma unroll
    for (int i = 0; i < 2; ++i)
#pragma unroll
      for (int j = 0; j < 4; ++j)
        acc[i][j] = __builtin_amdgcn_mfma_f32_16x16x32_bf16(af[i], bfr[j], acc[i][j], 0, 0, 0);
  }

#pragma unroll
  for (int i = 0; i < 2; ++i) {
    const int rowb = m0 + wm + i * 16 + quad * 4;
#pragma unroll
    for (int j = 0; j < 4; ++j) {
      const int col = n0 + wn + j * 16 + l16;
#pragma unroll
      for (int r = 0; r < 4; ++r)
        C[(size_t)(rowb + r) * N + col] += acc[i][j][r];
    }
  }
}

__global__ __launch_bounds__(256) void gemm_add(const bf16* __restrict__ A,
                                                const bf16* __restrict__ Wc,
                                                const bf16* __restrict__ Wo,
                                                const int* __restrict__ flag,
                                                float* __restrict__ C) {
  const bf16* W = (*flag != 0) ? Wc : Wo;
  gemm64_body(A, W, C, DIM, blockIdx.y * 64, blockIdx.x * 128);
}

// ---------------------------------------------------------------------------
// h = x + pe  (flag-dependent input dtype), fp32 residual stream
// ---------------------------------------------------------------------------
__global__ __launch_bounds__(256) void add_pe(const void* __restrict__ x,
                                              const void* __restrict__ pe,
                                              float* __restrict__ h,
                                              const int* __restrict__ flag) {
  const bool f32 = (*flag != 0);
  const size_t i = (size_t)blockIdx.x * 256 + threadIdx.x;
  h[i] = loadf(x, i, f32) + loadf(pe, i & (SEQ * DIM - 1), f32);
}

// ---------------------------------------------------------------------------
// LayerNorm over D=1024: one 256-thread block per row, fp32 in, bf16 out.
// ---------------------------------------------------------------------------
__global__ __launch_bounds__(256) void layernorm(const float* __restrict__ x,
                                                 const void* __restrict__ g,
                                                 const void* __restrict__ b,
                                                 int loff,
                                                 bf16* __restrict__ y,
                                                 const int* __restrict__ flag) {
  const bool f32 = (*flag != 0);
  const int row = blockIdx.x;
  const int tid = threadIdx.x;
  const int wave = tid >> 6;
  const float* xr = x + (size_t)row * DIM;
  __shared__ float red[8];

  float v[4];
  float s = 0.f;
#pragma unroll
  for (int i = 0; i < 4; ++i) { v[i] = xr[tid + 256 * i]; s += v[i]; }
#pragma unroll
  for (int off = 32; off >= 1; off >>= 1) s += __shfl_xor(s, off);
  if ((tid & 63) == 0) red[wave] = s;
  __syncthreads();
  const float mu = (red[0] + red[1] + red[2] + red[3]) * (1.f / DIM);

  float vs = 0.f;
#pragma unroll
  for (int i = 0; i < 4; ++i) { const float d = v[i] - mu; vs += d * d; }
#pragma unroll
  for (int off = 32; off >= 1; off >>= 1) vs += __shfl_xor(vs, off);
  if ((tid & 63) == 0) red[4 + wave] = vs;
  __syncthreads();
  const float var = (red[4] + red[5] + red[6] + red[7]) * (1.f / DIM);
  const float rs = rsqrtf(var + 1e-5f);

#pragma unroll
  for (int i = 0; i < 4; ++i) {
    const int d = tid + 256 * i;
    const float gv = loadf(g, (size_t)loff + d, f32);
    const float bv = loadf(b, (size_t)loff + d, f32);
    y[(size_t)row * DIM + d] = __float2bfloat16((v[i] - mu) * rs * gv + bv);
  }
}

// ---------------------------------------------------------------------------
// MFMA flash attention, FIXED-MAX softmax (m=0): scores bounded (|s|<=26),
// so no max reduction, no alpha rescale; l reduced once at the end.
// Block = (b, h, 64 q-rows); 4 waves, 16 q-rows/wave.
// ---------------------------------------------------------------------------
__global__ __launch_bounds__(256, 2) void attn_flash(const bf16* __restrict__ q,
                                                     const bf16* __restrict__ k,
                                                     const bf16* __restrict__ v,
                                                     bf16* __restrict__ o) {
  __shared__ __align__(16) short lK[64 * 64];        // [key][dim], chunk-swizzled
  __shared__ __align__(16) short lVT[64 * VTS];      // [dim][key], kk-swizzled
  __shared__ __align__(16) short lP[4 * 16 * VTS];   // per-wave P, padded

  const int idx = blockIdx.x;
  const int qt = (SEQ / 64 - 1) - (idx >> 6);        // heavy blocks first
  const int bh = idx & 63;
  const int hh = bh & (NH - 1);
  const int bb = bh >> 4;
  const int q0 = qt * 64;

  const int tid = threadIdx.x;
  const int wave = tid >> 6;
  const int lane = tid & 63;
  const int quad = lane >> 4;
  const int l16 = lane & 15;

  const size_t base = (size_t)bb * SEQ * DIM + hh * HDIM;
  const int qlo = q0 + wave * 16;                    // this wave's first q row

  // Q fragments (A-layout: m=l16, k=quad*8+j), pre-scaled by 1/sqrt(HD)
  bf16x8 qf[2];
  {
    const bf16* qr = q + base + (size_t)(qlo + l16) * DIM;
#pragma unroll
    for (int kc = 0; kc < 2; ++kc) {
      bf16x8 t = *(const bf16x8*)(qr + kc * 32 + quad * 8);
      bf16x8 sq;
#pragma unroll
      for (int e = 0; e < 8; ++e) sq[e] = f2bs(bf2f(t[e]) * 0.125f);
      qf[kc] = sq;
    }
  }

  float l_acc[4] = {0.f, 0.f, 0.f, 0.f};   // per-lane partial sums (rows)
  f32x4 oacc[4];
#pragma unroll
  for (int nb = 0; nb < 4; ++nb) oacc[nb] = (f32x4){0.f, 0.f, 0.f, 0.f};

  short* lPw = lP + wave * 16 * VTS;
  const int nt = qt + 1;

  for (int t = 0; t < nt; ++t) {
    const int kbase = t * 64;
    __syncthreads();   // previous tile's LDS reads complete

    // --- stage K tile [64 keys][64 dims] via g2l16, chunk-swizzled
    {
      const int r8 = lane >> 3;                 // row within 8-row group
      const int cc = (lane & 7) ^ r8;           // swizzled 16B chunk
#pragma unroll
      for (int c = 0; c < 2; ++c) {
        const int row = wave * 16 + c * 8 + r8; // key within tile
        g2l16(k + base + (size_t)(kbase + row) * DIM + cc * 8,
              lK + (wave * 16 + c * 8) * 64);
      }
    }

    // --- stage V^T [dim][key] via regs, kk XOR-swizzled by (dim>>3)&7
    bf16x8 vch[2];
#pragma unroll
    for (int c2 = 0; c2 < 2; ++c2) {
      const int cid = tid + c2 * 256;
      const int kk = cid >> 3;
      const int d0 = (cid & 7) * 8;
      vch[c2] = *(const bf16x8*)(v + base + (size_t)(kbase + kk) * DIM + d0);
    }
#pragma unroll
    for (int c2 = 0; c2 < 2; ++c2) {
      const int cid = tid + c2 * 256;
      const int kk = cid >> 3;
      const int d0 = (cid & 7) * 8;
#pragma unroll
      for (int e = 0; e < 8; ++e) {
        const int d = d0 + e;
        const int kks = kk ^ (((d >> 3) & 7) << 3);
        lVT[d * VTS + kks] = vch[c2][e];
      }
    }
    __builtin_amdgcn_s_waitcnt(0);   // drain g2l16 before barrier
    __syncthreads();

    // --- S = Q K^T : 16 q-rows x 64 keys per wave
    f32x4 s[4];
#pragma unroll
    for (int nb = 0; nb < 4; ++nb) {
      f32x4 acc = (f32x4){0.f, 0.f, 0.f, 0.f};
      const int n = nb * 16 + l16;              // key within tile
#pragma unroll
      for (int kc = 0; kc < 2; ++kc) {
        const int cidx = (kc * 4 + quad) ^ (n & 7);
        bf16x8 kf = *(const bf16x8*)(lK + n * 64 + cidx * 8);
        acc = __builtin_amdgcn_mfma_f32_16x16x32_bf16(qf[kc], kf, acc, 0, 0, 0);
      }
      s[nb] = acc;
    }

    // --- causal mask (only the diagonal tile needs it)
    if (kbase + 63 > qlo) {
#pragma unroll
      for (int nb = 0; nb < 4; ++nb) {
        const int j = kbase + nb * 16 + l16;
#pragma unroll
        for (int r = 0; r < 4; ++r)
          if (j > qlo + quad * 4 + r) s[nb][r] = NEG_BIG;
      }
    }

    // --- fixed-max softmax: p = exp(s); accumulate l per-lane; P -> LDS
#pragma unroll
    for (int nb = 0; nb < 4; ++nb) {
#pragma unroll
      for (int r = 0; r < 4; ++r) {
        const float p = exp_clamped(s[nb][r]);
        l_acc[r] += p;
        lPw[(quad * 4 + r) * VTS + nb * 16 + l16] = f2bs(p);
      }
    }

    // --- P back from LDS in A-layout (same wave; lgkm drain)
    __builtin_amdgcn_s_waitcnt(0);
    bf16x8 pf[2];
#pragma unroll
    for (int kc = 0; kc < 2; ++kc)
      pf[kc] = *(const bf16x8*)(lPw + l16 * VTS + kc * 32 + quad * 8);

    // --- O += P V  (b-frag from V^T rows, undo kk swizzle)
#pragma unroll
    for (int nb = 0; nb < 4; ++nb) {
      const int n = nb * 16 + l16;              // output dim
      const int swz = ((n >> 3) & 7) << 3;
#pragma unroll
      for (int kc = 0; kc < 2; ++kc) {
        const int kchunk = (kc * 32 + quad * 8) ^ swz;
        bf16x8 vf = *(const bf16x8*)(lVT + n * VTS + kchunk);
        oacc[nb] = __builtin_amdgcn_mfma_f32_16x16x32_bf16(pf[kc], vf, oacc[nb], 0, 0, 0);
      }
    }
  }

  // --- reduce l across the 16-lane key groups (once), normalize, store
  float linv[4];
#pragma unroll
  for (int r = 0; r < 4; ++r) {
    float ts = l_acc[r];
#pragma unroll
    for (int off = 8; off >= 1; off >>= 1) ts += __shfl_xor(ts, off);
    linv[r] = 1.f / ts;
  }
#pragma unroll
  for (int nb = 0; nb < 4; ++nb)
#pragma unroll
    for (int r = 0; r < 4; ++r) {
      const int qrow = q0 + wave * 16 + quad * 4 + r;
      o[base + (size_t)qrow * DIM + nb * 16 + l16] =
          __float2bfloat16(oacc[nb][r] * linv[r]);
    }
}

// ---------------------------------------------------------------------------
extern "C" void kernel_launch(void* const* d_in, const int* in_sizes, int n_in,
                              void* d_out, int out_size, void* d_ws, size_t ws_size,
                              hipStream_t stream) {
  const void* x    = d_in[0];
  const void* pe   = d_in[1];
  // d_in[2] = mask (causal; handled analytically; never read)
  const void* ln1g = d_in[3];
  const void* ln1b = d_in[4];
  const void* wq   = d_in[5];
  const void* wk   = d_in[6];
  const void* wv   = d_in[7];
  const void* wo   = d_in[8];
  const void* ln2g = d_in[9];
  const void* ln2b = d_in[10];
  const void* wf   = d_in[11];
  const void* lnfg = d_in[12];
  const void* lnfb = d_in[13];
  const void* wout = d_in[14];

  const size_t MB = 1u << 20;
  char* ws = (char*)d_ws;
  int*  flag = (int*)ws;                          // 4 B (1 MB reserved)
  bf16* wqc  = (bf16*)(ws + 1 * MB);              // 12 MB (6 layers)
  bf16* wkc  = (bf16*)(ws + 13 * MB);
  bf16* wvc  = (bf16*)(ws + 25 * MB);
  bf16* woc  = (bf16*)(ws + 37 * MB);
  bf16* wfc  = (bf16*)(ws + 49 * MB);
  bf16* woutc= (bf16*)(ws + 61 * MB);             // 1 MB
  float* h   = (float*)(ws + 62 * MB);            // 16 MB fp32 residual
  bf16* hn   = (bf16*)(ws + 78 * MB);             // 8 MB
  bf16* qb   = (bf16*)(ws + 86 * MB);
  bf16* kb   = (bf16*)(ws + 94 * MB);
  bf16* vb   = (bf16*)(ws + 102 * MB);            // end: 110 MB
  bf16* ab   = hn;   // attn out aliases hn (ln1 output dead after QKV gemm)

  sniff<<<1, 64, 0, stream>>>((const unsigned int*)wq, flag);

  // weight convert: early-exit when inputs are bf16 (GEMMs then read the
  // original buffers directly); vectorized grid-stride when fp32.
  convert_all<<<2048, 256, 0, stream>>>(
      (const float*)wq, (const float*)wk, (const float*)wv,
      (const float*)wo, (const float*)wf, (const float*)wout,
      wqc, wkc, wvc, woc, wfc, woutc, flag);

  add_pe<<<NTOK * DIM / 256, 256, 0, stream>>>(x, pe, h, flag);

  for (int l = 0; l < NLAYER; ++l) {
    const size_t woff = (size_t)l << 20;          // l * 1024*1024 elements
    const int poff = l * DIM;                     // element offset for gamma/beta
    layernorm<<<NTOK, 256, 0, stream>>>(h, ln1g, ln1b, poff, hn, flag);
    gemm_qkv<<<dim3(24, 32), 256, 0, stream>>>(
        hn, wqc + woff, wkc + woff, wvc + woff,
        (const bf16*)wq + woff, (const bf16*)wk + woff, (const bf16*)wv + woff,
        qb, kb, vb, flag);
    attn_flash<<<dim3(BATCH * NH * (SEQ / 64)), 256, 0, stream>>>(qb, kb, vb, ab);
    gemm_add<<<dim3(8, 64), 256, 0, stream>>>(ab, woc + woff,
                                              (const bf16*)wo + woff, flag, h);
    layernorm<<<NTOK, 256, 0, stream>>>(h, ln2g, ln2b, poff, hn, flag);
    gemm_add<<<dim3(8, 64), 256, 0, stream>>>(hn, wfc + woff,
                                              (const bf16*)wf + woff, flag, h);
  }

  layernorm<<<NTOK, 256, 0, stream>>>(h, lnfg, lnfb, 0, hn, flag);
  gemm_out<<<dim3(4, 32), 256, 0, stream>>>(hn, woutc, (const bf16*)wout,
                                            d_out, flag);
}